// Round 4
// baseline (1687.231 us; speedup 1.0000x reference)
//
#include <hip/hip_runtime.h>

// Problem constants
#define BSZ   128
#define NTOK  512
#define SDIM  256
#define PDIM  128
#define FDIM  256
#define NIT   30

typedef _Float16 half_t;
typedef _Float16 half8_t __attribute__((ext_vector_type(8)));

// =====================================================================
// K0: transpose W [256,128] -> Wt [128,256]
// =====================================================================
__global__ __launch_bounds__(256) void transpose_w_kernel(const float* __restrict__ W,
                                                          float* __restrict__ Wt) {
    int idx = blockIdx.x * 256 + threadIdx.x;   // [0, 32768)
    int d = idx >> 7;        // 0..255
    int p = idx & 127;       // 0..127
    Wt[p * 256 + d] = W[idx];
}

// =====================================================================
// K1: h = X@W + b -> LayerNorm -> *g+beta -> l2norm.
// =====================================================================
__global__ __launch_bounds__(256) void proj_kernel(const float* __restrict__ X,
                                                   const float* __restrict__ Wt,
                                                   const float* __restrict__ bias,
                                                   const float* __restrict__ gamma,
                                                   const float* __restrict__ beta,
                                                   float* __restrict__ out) {
    __shared__ float sX[32 * 66];
    __shared__ float sB[128 * 66];
    const int t = threadIdx.x;
    const int row0 = blockIdx.x * 32;
    const int cg = t & 31;      // col group
    const int rg = t >> 5;      // 0..7
    float acc[4][4] = {};

    for (int dc = 0; dc < 4; ++dc) {   // 4 k-chunks of 64
#pragma unroll
        for (int i = 0; i < 2; ++i) {  // stage 32x64 X chunk
            int e = t + 256 * i;
            int r = e >> 4, k4 = (e & 15) * 4;
            float4 v = *(const float4*)&X[(size_t)(row0 + r) * 256 + dc * 64 + k4];
            float* dst = &sX[r * 66 + k4];
            dst[0] = v.x; dst[1] = v.y; dst[2] = v.z; dst[3] = v.w;
        }
#pragma unroll
        for (int i = 0; i < 8; ++i) {  // stage 128x64 W chunk
            int e = t + 256 * i;
            int c = e >> 4, k4 = (e & 15) * 4;
            float4 v = *(const float4*)&Wt[(size_t)c * 256 + dc * 64 + k4];
            float* dst = &sB[c * 66 + k4];
            dst[0] = v.x; dst[1] = v.y; dst[2] = v.z; dst[3] = v.w;
        }
        __syncthreads();
#pragma unroll 8
        for (int kk = 0; kk < 64; kk += 2) {
            float2 a2[4], b2[4];
#pragma unroll
            for (int j = 0; j < 4; ++j) b2[j] = *(const float2*)&sB[(cg + 32 * j) * 66 + kk];
#pragma unroll
            for (int i = 0; i < 4; ++i) a2[i] = *(const float2*)&sX[(rg + 8 * i) * 66 + kk];
#pragma unroll
            for (int i = 0; i < 4; ++i)
#pragma unroll
                for (int j = 0; j < 4; ++j)
                    acc[i][j] += a2[i].x * b2[j].x + a2[i].y * b2[j].y;
        }
        __syncthreads();
    }

    float bia[4], gam[4], bet[4];
#pragma unroll
    for (int j = 0; j < 4; ++j) {
        int c = cg + 32 * j;
        bia[j] = bias[c]; gam[j] = gamma[c]; bet[j] = beta[c];
    }

#pragma unroll
    for (int i = 0; i < 4; ++i) {
        int r = rg + 8 * i;
        float h[4];
        float s1 = 0.f, s2 = 0.f;
#pragma unroll
        for (int j = 0; j < 4; ++j) {
            h[j] = acc[i][j] + bia[j];
            s1 += h[j];
            s2 += h[j] * h[j];
        }
        for (int m = 1; m < 32; m <<= 1) {
            s1 += __shfl_xor(s1, m);
            s2 += __shfl_xor(s2, m);
        }
        float mu  = s1 * (1.f / 128.f);
        float var = s2 * (1.f / 128.f) - mu * mu;
        float rstd = 1.f / sqrtf(var + 1e-5f);
        float y[4]; float s3 = 0.f;
#pragma unroll
        for (int j = 0; j < 4; ++j) {
            y[j] = (h[j] - mu) * rstd * gam[j] + bet[j];
            s3 += y[j] * y[j];
        }
        for (int m = 1; m < 32; m <<= 1) s3 += __shfl_xor(s3, m);
        float inv = 1.f / fmaxf(sqrtf(s3), 1e-12f);
#pragma unroll
        for (int j = 0; j < 4; ++j)
            out[(size_t)(row0 + r) * 128 + cg + 32 * j] = y[j] * inv;
    }
}

// =====================================================================
// K2: K[b,n,m] = exp(-clip(1 - Sp[b,n].Fp[b,m],0,2)/0.1)
// =====================================================================
__global__ __launch_bounds__(256) void cosk_kernel(const float* __restrict__ SP,
                                                   const float* __restrict__ FP,
                                                   float* __restrict__ Kout,
                                                   half_t* __restrict__ K16out) {
    const int b = blockIdx.y;
    const int tile = blockIdx.x;
    const int n0 = (tile >> 3) * 64, m0 = (tile & 7) * 64;
    __shared__ float sA[64 * 66];
    __shared__ float sB[64 * 66];
    const float* A  = SP + (size_t)b * NTOK * PDIM;
    const float* Bm = FP + (size_t)b * NTOK * PDIM;
    const int t = threadIdx.x;
    const int mg = t & 15, ng = t >> 4;
    float acc[4][4] = {};

    for (int kc = 0; kc < 2; ++kc) {   // 2 k-chunks of 64 (PDIM=128)
#pragma unroll
        for (int i = 0; i < 4; ++i) {
            int e = t + 256 * i;           // 0..1023
            int r = e >> 4, k4 = (e & 15) * 4;
            float4 va = *(const float4*)&A [(size_t)(n0 + r) * 128 + kc * 64 + k4];
            float4 vb = *(const float4*)&Bm[(size_t)(m0 + r) * 128 + kc * 64 + k4];
            float* da = &sA[r * 66 + k4];
            da[0] = va.x; da[1] = va.y; da[2] = va.z; da[3] = va.w;
            float* db = &sB[r * 66 + k4];
            db[0] = vb.x; db[1] = vb.y; db[2] = vb.z; db[3] = vb.w;
        }
        __syncthreads();
#pragma unroll 8
        for (int kk = 0; kk < 64; kk += 2) {
            float2 a2[4], b2[4];
#pragma unroll
            for (int i = 0; i < 4; ++i) a2[i] = *(const float2*)&sA[(ng + 16 * i) * 66 + kk];
#pragma unroll
            for (int j = 0; j < 4; ++j) b2[j] = *(const float2*)&sB[(mg + 16 * j) * 66 + kk];
#pragma unroll
            for (int i = 0; i < 4; ++i)
#pragma unroll
                for (int j = 0; j < 4; ++j)
                    acc[i][j] += a2[i].x * b2[j].x + a2[i].y * b2[j].y;
        }
        __syncthreads();
    }

#pragma unroll
    for (int i = 0; i < 4; ++i) {
        int n = n0 + ng + 16 * i;
#pragma unroll
        for (int j = 0; j < 4; ++j) {
            int m = m0 + mg + 16 * j;
            float C = fminf(fmaxf(1.f - acc[i][j], 0.f), 2.f);
            float K = expf(-10.f * C);
            size_t gidx = ((size_t)b * NTOK + n) * NTOK + m;
            Kout[gidx] = K;
            K16out[gidx] = (half_t)K;
        }
    }
}

// =====================================================================
// K3 (FUSED 30-iteration Sinkhorn, intra-block only): 128 blocks x 1024.
// Block b owns batch element b entirely (K16 slice = 512 KB, L2/L3-hot).
// Wave w (0..15) owns rows w*32..w*32+31; per row: full 512-elem dot
// (64 lanes x 8) + 6-step xor-butterfly; K^T u column partials kept per
// lane; 16-wave combine + v-update in LDS.  ONLY __syncthreads -- no
// cross-block sync, cannot hang.
// LDS layout swizzle sw(m) = (m&7)*64 + (m>>3) for vs and wacc columns:
// every LDS access (vl fetch, colacc write, 16-wave sum) is stride-1
// across lanes -> bank-conflict-free.
// __launch_bounds__(1024,4): 16 waves/block = 4 waves/SIMD -> VGPR<=128
// (body needs ~95, same as r2 -- no spill).
// =====================================================================
__global__ __launch_bounds__(1024, 4) void sinkhorn_fused_kernel(const half_t* __restrict__ K16,
                                                                 float* __restrict__ U,
                                                                 float* __restrict__ VFIN) {
    const int b = blockIdx.x;
    const int t = threadIdx.x;
    const int wave = t >> 6, lane = t & 63;    // wave 0..15

    __shared__ float vs[NTOK];                 // swizzled: vs[sw(m)]
    __shared__ float wacc[16][NTOK];           // swizzled cols; 32 KB

    const half_t* Kbase = K16 + ((size_t)b * NTOK + wave * 32) * NTOK + lane * 8;

    if (t < NTOK) vs[t] = 1.f;                 // v0 = ones (swizzle-invariant)
    __syncthreads();

    float ureg = 0.f;

    for (int it = 0; it < NIT; ++it) {
        // vl[j] = v[lane*8 + j]; sw(lane*8+j) = j*64 + lane -> stride-1/lane
        float vl[8];
#pragma unroll
        for (int j = 0; j < 8; ++j) vl[j] = vs[j * 64 + lane];

        // ---- K stream: 8 groups of 4 rows, depth-2 lookahead ----
        half8_t buf[3][4];
#pragma unroll
        for (int r = 0; r < 4; ++r) buf[0][r] = *(const half8_t*)(Kbase + (size_t)r * NTOK);
#pragma unroll
        for (int r = 0; r < 4; ++r) buf[1][r] = *(const half8_t*)(Kbase + (size_t)(4 + r) * NTOK);

        float colacc[8] = {};

#pragma unroll
        for (int g = 0; g < 8; ++g) {
            if (g < 6) {
#pragma unroll
                for (int r = 0; r < 4; ++r)
                    buf[(g + 2) % 3][r] = *(const half8_t*)(Kbase + (size_t)((g + 2) * 4 + r) * NTOK);
            }
            float p[4];
#pragma unroll
            for (int rr = 0; rr < 4; ++rr) {
                const half8_t kk = buf[g % 3][rr];
                float d0 = (float)kk[0] * vl[0] + (float)kk[1] * vl[1];
                float d1 = (float)kk[2] * vl[2] + (float)kk[3] * vl[3];
                float d2 = (float)kk[4] * vl[4] + (float)kk[5] * vl[5];
                float d3 = (float)kk[6] * vl[6] + (float)kk[7] * vl[7];
                p[rr] = (d0 + d1) + (d2 + d3);
            }
#pragma unroll
            for (int m = 1; m < 64; m <<= 1)
#pragma unroll
                for (int rr = 0; rr < 4; ++rr)
                    p[rr] += __shfl_xor(p[rr], m);
#pragma unroll
            for (int rr = 0; rr < 4; ++rr) {
                float u_r = (1.f / 512.f) / (p[rr] + 1e-8f);
                if (lane == g * 4 + rr) ureg = u_r;   // lanes 0..31 hold their row's u
#pragma unroll
                for (int j = 0; j < 8; ++j)
                    colacc[j] += (float)buf[g % 3][rr][j] * u_r;
            }
        }

        // colacc[j] is col m = lane*8+j -> swizzled index j*64+lane (stride-1)
#pragma unroll
        for (int j = 0; j < 8; ++j) wacc[wave][j * 64 + lane] = colacc[j];
        __syncthreads();

        // ---- combine 16 waves -> v (threads 0..511, conflict-free) ----
        if (t < NTOK) {
            float sum = 0.f;
#pragma unroll
            for (int w = 0; w < 16; ++w) sum += wacc[w][t];
            float v = (1.f / 512.f) / (sum + 1e-8f);
            v = fminf(fmaxf(v, 1e-8f), 1e8f);
            if (it < NIT - 1) {
                vs[t] = v;
            } else {
                int m = ((t & 63) << 3) | (t >> 6);      // unswizzle
                VFIN[(size_t)b * NTOK + m] = v;          // final clipped v
            }
        }
        if (it == NIT - 1 && lane < 32)
            U[(size_t)b * NTOK + wave * 32 + lane] = ureg;   // raw u (clip in final)
        __syncthreads();   // vs update visible / wacc reusable
    }
}

// =====================================================================
// K5: final.  8 rows x 8 cols register tile (halves ds_read count vs
// 16x4 -> DS pipe below VALU floor).  Software-pipelined K-chunk loads
// + double-buffered sP.  v comes precomputed (clipped) from VFIN.
// NOTE: FT writes land exactly on this strip's K16 bytes (FT region) --
// K16 is dead after the sinkhorn loop, and final reads only K32.
// =====================================================================
__global__ __launch_bounds__(256) void final_kernel(const float* __restrict__ vfin,
                                                    const float* __restrict__ u,
                                                    const float* __restrict__ F,
                                                    float* __restrict__ Pout,
                                                    float* __restrict__ FTout) {
    const int blk = blockIdx.x;
    const int b = blk >> 3, s = blk & 7;
    __shared__ float vs[NTOK];
    __shared__ float us[64];
    __shared__ float sP[2][64 * 68];
    const int t = threadIdx.x;

    for (int m = t; m < NTOK; m += 256)
        vs[m] = vfin[(size_t)b * NTOK + m];          // already clipped
    if (t < 64) {
        float uu = u[(size_t)b * NTOK + s * 64 + t];
        us[t] = fminf(fmaxf(uu, 1e-8f), 1e8f);
    }

    const int cg = t & 31;   // F cols 8*cg..+8
    const int rg = t >> 5;   // rows 8*rg..+8
    const float* Fb = F + (size_t)b * NTOK * FDIM;
    float* Pbase = Pout + ((size_t)b * NTOK + s * 64) * NTOK;

    float4 kreg[4];
    auto issue_load = [&](int mc) {
#pragma unroll
        for (int i = 0; i < 4; ++i) {
            int e = t + 256 * i;            // 0..1023 float4 slots
            int r = e >> 4, m4 = (e & 15) * 4;
            kreg[i] = *(const float4*)&Pbase[(size_t)r * NTOK + mc * 64 + m4];
        }
    };
    auto emit = [&](int mc, int bufi) {     // P = u*K*v -> global (in place) + LDS
#pragma unroll
        for (int i = 0; i < 4; ++i) {
            int e = t + 256 * i;
            int r = e >> 4, m4 = (e & 15) * 4;
            float ur = us[r];
            float4 p4;
            p4.x = kreg[i].x * ur * vs[mc * 64 + m4 + 0];
            p4.y = kreg[i].y * ur * vs[mc * 64 + m4 + 1];
            p4.z = kreg[i].z * ur * vs[mc * 64 + m4 + 2];
            p4.w = kreg[i].w * ur * vs[mc * 64 + m4 + 3];
            *(float4*)&Pbase[(size_t)r * NTOK + mc * 64 + m4] = p4;
            float* dst = &sP[bufi][r * 68 + m4];
            dst[0] = p4.x; dst[1] = p4.y; dst[2] = p4.z; dst[3] = p4.w;
        }
    };

    float acc[8][8] = {};

    issue_load(0);
    __syncthreads();          // vs/us visible
    emit(0, 0);
    __syncthreads();
    int cur = 0;

    for (int mc = 0; mc < 8; ++mc) {
        if (mc < 7) issue_load(mc + 1);     // next chunk's K in flight during GEMM

        const float* Fc = Fb + (size_t)(mc * 64) * FDIM + 8 * cg;
        const float* sp = &sP[cur][(rg * 8) * 68];
        for (int mm = 0; mm < 64; mm += 4) {
            float4 fa0 = *(const float4*)&Fc[(size_t)(mm + 0) * FDIM];
            float4 fb0 = *(const float4*)&Fc[(size_t)(mm + 0) * FDIM + 4];
            float4 fa1 = *(const float4*)&Fc[(size_t)(mm + 1) * FDIM];
            float4 fb1 = *(const float4*)&Fc[(size_t)(mm + 1) * FDIM + 4];
            float4 fa2 = *(const float4*)&Fc[(size_t)(mm + 2) * FDIM];
            float4 fb2 = *(const float4*)&Fc[(size_t)(mm + 2) * FDIM + 4];
            float4 fa3 = *(const float4*)&Fc[(size_t)(mm + 3) * FDIM];
            float4 fb3 = *(const float4*)&Fc[(size_t)(mm + 3) * FDIM + 4];
#pragma unroll
            for (int i = 0; i < 8; ++i) {
                float4 p = *(const float4*)&sp[i * 68 + mm];
                acc[i][0] += p.x * fa0.x + p.y * fa1.x + p.z * fa2.x + p.w * fa3.x;
                acc[i][1] += p.x * fa0.y + p.y * fa1.y + p.z * fa2.y + p.w * fa3.y;
                acc[i][2] += p.x * fa0.z + p.y * fa1.z + p.z * fa2.z + p.w * fa3.z;
                acc[i][3] += p.x * fa0.w + p.y * fa1.w + p.z * fa2.w + p.w * fa3.w;
                acc[i][4] += p.x * fb0.x + p.y * fb1.x + p.z * fb2.x + p.w * fb3.x;
                acc[i][5] += p.x * fb0.y + p.y * fb1.y + p.z * fb2.y + p.w * fb3.y;
                acc[i][6] += p.x * fb0.z + p.y * fb1.z + p.z * fb2.z + p.w * fb3.z;
                acc[i][7] += p.x * fb0.w + p.y * fb1.w + p.z * fb2.w + p.w * fb3.w;
            }
        }

        if (mc < 7) {
            emit(mc + 1, cur ^ 1);
            __syncthreads();
            cur ^= 1;
        }
    }

#pragma unroll
    for (int i = 0; i < 8; ++i) {
        float4 o0, o1;
        o0.x = acc[i][0]; o0.y = acc[i][1]; o0.z = acc[i][2]; o0.w = acc[i][3];
        o1.x = acc[i][4]; o1.y = acc[i][5]; o1.z = acc[i][6]; o1.w = acc[i][7];
        size_t row = (size_t)b * NTOK + s * 64 + rg * 8 + i;
        *(float4*)&FTout[row * FDIM + 8 * cg]     = o0;
        *(float4*)&FTout[row * FDIM + 8 * cg + 4] = o1;
    }
}

// =====================================================================
extern "C" void kernel_launch(void* const* d_in, const int* in_sizes, int n_in,
                              void* d_out, int out_size, void* d_ws, size_t ws_size,
                              hipStream_t stream) {
    const float* S      = (const float*)d_in[0];
    const float* F      = (const float*)d_in[1];
    const float* W_s    = (const float*)d_in[2];
    const float* b_s    = (const float*)d_in[3];
    const float* g_s    = (const float*)d_in[4];
    const float* beta_s = (const float*)d_in[5];
    const float* W_f    = (const float*)d_in[6];
    const float* b_f    = (const float*)d_in[7];
    const float* g_f    = (const float*)d_in[8];
    const float* beta_f = (const float*)d_in[9];

    float* wsf  = (float*)d_ws;
    float* WT_s = wsf;                        // 32768
    float* WT_f = wsf + 32768;                // 32768
    float* SP   = wsf + 65536;                // 65536*128
    float* FP   = SP + (size_t)65536 * 128;   // 65536*128
    float* U    = FP + (size_t)65536 * 128;   // 65536
    float* VFIN = U + 65536;                  // 65536 (final clipped v)

    float* Pout = (float*)d_out;                      // [128,512,512] (K32 then P, in place)
    float* FT   = Pout + (size_t)BSZ * NTOK * NTOK;   // [128,512,256]
    // fp16 K lives in the FT region during the sinkhorn phase:
    // 128*512*512*2 bytes == 128*512*256*4 bytes exactly.
    half_t* K16 = (half_t*)FT;

    transpose_w_kernel<<<128, 256, 0, stream>>>(W_s, WT_s);
    transpose_w_kernel<<<128, 256, 0, stream>>>(W_f, WT_f);

    proj_kernel<<<2048, 256, 0, stream>>>(S, WT_s, b_s, g_s, beta_s, SP);
    proj_kernel<<<2048, 256, 0, stream>>>(F, WT_f, b_f, g_f, beta_f, FP);

    cosk_kernel<<<dim3(64, 128), 256, 0, stream>>>(SP, FP, Pout, K16);

    // all 30 iterations in ONE dispatch; block b owns batch element b.
    sinkhorn_fused_kernel<<<128, 1024, 0, stream>>>(K16, U, VFIN);

    final_kernel<<<1024, 256, 0, stream>>>(VFIN, U, F, Pout, FT);
}